// Round 8
// baseline (925.969 us; speedup 1.0000x reference)
//
#include <hip/hip_runtime.h>
#include <hip/hip_bf16.h>
#include <math.h>

#define BATCH 8
#define NATOMS 192
#define HF 32

using short8 = __attribute__((ext_vector_type(8))) short;
using f32x4  = __attribute__((ext_vector_type(4))) float;

__device__ __forceinline__ float fast_rcp(float x){ return __builtin_amdgcn_rcpf(x); }
__device__ __forceinline__ float sigmoid_f(float x){ return fast_rcp(1.0f+__expf(-x)); }
__device__ __forceinline__ float silu_f(float x){ return x*fast_rcp(1.0f+__expf(-x)); }
__device__ __forceinline__ float softplus_f(float x){ return fmaxf(x,0.0f)+log1pf(expf(-fabsf(x))); }
__device__ __forceinline__ unsigned short f2bf(float x){
  __hip_bfloat16 h = __float2bfloat16(x);
  return __builtin_bit_cast(unsigned short, h);
}

__device__ __forceinline__ float wave_sum(float v){
  v += __shfl_xor(v, 1);
  v += __shfl_xor(v, 2);
  v += __shfl_xor(v, 4);
  v += __shfl_xor(v, 8);
  v += __shfl_xor(v, 16);
  v += __shfl_xor(v, 32);
  return v;
}

// ------ prelude: 0..79 pdf dot (b,o); 80..87 gamma(b); 88..103 bf16 wprep ---
__global__ __launch_bounds__(256) void k_prelude(
    const float* __restrict__ pdf, const float* __restrict__ t,
    const float* __restrict__ pdf_w, const float* __restrict__ pdf_b,
    const float* __restrict__ g1w, const float* __restrict__ g1b,
    const float* __restrict__ g2w, const float* __restrict__ g2b,
    const float* __restrict__ g3w, const float* __restrict__ g3b,
    const float* __restrict__ gamma0, const float* __restrict__ gamma1,
    const float* __restrict__ e2w, const float* __restrict__ c2w,
    unsigned short* __restrict__ e2wb, unsigned short* __restrict__ c2wb,
    float* __restrict__ temb, float* __restrict__ pdfe)
{
  __shared__ float lds[4];
  const int bx = blockIdx.x, tid = threadIdx.x;
  const int wv = tid >> 6, ln = tid & 63;

  if (bx >= 88){
    const int g = (bx - 88)*256 + tid;   // 4096 elements each
    e2wb[g] = f2bf(e2w[g]);
    c2wb[g] = f2bf(c2w[g]);
    return;
  }
  if (bx < 80){
    const int b = bx / 10, o = bx % 10;
    const float* pb = pdf + b*3000;
    const float* wb = pdf_w + o*3000;
    float p = 0.f;
    for (int k = tid; k < 3000; k += 256) p = fmaf(pb[k], wb[k], p);
    p = wave_sum(p);
    if (ln == 0) lds[wv] = p;
    __syncthreads();
    if (tid == 0) pdfe[b*10 + o] = lds[0] + lds[1] + lds[2] + lds[3] + pdf_b[o];
    return;
  }
  const int b = bx - 80;
  const float w1 = softplus_f(g1w[0]);
  const float b1 = g1b[0];
  const float tn = t[b] * (1.0f/1000.0f);
  const float l1_0 = b1;
  const float l1_1 = w1 + b1;
  const float l1_t = fmaf(w1, tn, b1);
  float a0 = 0.f, a1 = 0.f, at = 0.f;
  for (int k = tid; k < 1024; k += 256){
    float w2 = softplus_f(g2w[k]);
    float bb = g2b[k];
    float w3 = softplus_f(g3w[k]);
    a0 += sigmoid_f(fmaf(w2, l1_0, bb)) * w3;
    a1 += sigmoid_f(fmaf(w2, l1_1, bb)) * w3;
    at += sigmoid_f(fmaf(w2, l1_t, bb)) * w3;
  }
  float sums[3]; float vals[3] = {a0, a1, at};
  for (int r = 0; r < 3; ++r){
    float v = wave_sum(vals[r]);
    __syncthreads();
    if (ln == 0) lds[wv] = v;
    __syncthreads();
    sums[r] = lds[0] + lds[1] + lds[2] + lds[3];
  }
  if (tid == 0){
    const float b3 = g3b[0];
    const float g0 = l1_0 + sums[0] + b3;
    const float g1v = l1_1 + sums[1] + b3;
    const float gt = l1_t + sums[2] + b3;
    temb[b] = gamma0[0] + (gamma1[0] - gamma0[0]) * (gt - g0) / (g1v - g0);
  }
}

// ---- embed + layer-0 node precompute fused (h0 lives only in LDS) ----------
// 256 thr = 8 nodes x 32 f. Also zeroes the per-node atomic counters.
__global__ __launch_bounds__(256) void k_embed_node(
    const float* __restrict__ xyz, const float* __restrict__ temb,
    const float* __restrict__ pdfe, const float* __restrict__ wi,
    const float* __restrict__ bi,
    const float* __restrict__ lnhg, const float* __restrict__ lnhb,
    const float* __restrict__ e1w, const float* __restrict__ e1b,
    const float* __restrict__ c1w, const float* __restrict__ c1b,
    float* __restrict__ x, float* __restrict__ hln,
    float* __restrict__ ue, float* __restrict__ uc,
    float* __restrict__ vep, float* __restrict__ vcp,
    int* __restrict__ cnt)
{
  __shared__ float s_h[8][33];
  const int tid = threadIdx.x;
  const int il = tid >> 5, f = tid & 31;
  const int node = blockIdx.x*8 + il;
  const int b = node / NATOMS;

  {
    const float sp = xyz[node*4 + 3];
    const float* w = wi + f*12;
    float a = bi[f];
    a = fmaf(sp, w[0], a);
    a = fmaf(temb[b], w[1], a);
    const float* pe = pdfe + b*10;
#pragma unroll
    for (int p = 0; p < 10; ++p) a = fmaf(pe[p], w[2+p], a);
    s_h[il][f] = a;
  }
  if (f < 3) x[node*3 + f] = xyz[node*4 + f];
  if (f == 0) cnt[node] = 0;
  __syncthreads();

  float hl[32];
  float m = 0.f;
#pragma unroll
  for (int k = 0; k < 32; ++k){ hl[k] = s_h[il][k]; m += hl[k]; }
  m *= (1.0f/32.0f);
  float v = 0.f;
#pragma unroll
  for (int k = 0; k < 32; ++k){ float d = hl[k]-m; v = fmaf(d, d, v); }
  float r = rsqrtf(v*(1.0f/32.0f) + 1e-5f);
#pragma unroll
  for (int k = 0; k < 32; ++k) hl[k] = fmaf((hl[k]-m)*r, lnhg[k], lnhb[k]);
  hln[node*32 + f] = hl[f];

  const float* we = e1w + f*66;
  float sv = e1b[f], su = 0.f;
#pragma unroll
  for (int k = 0; k < 32; ++k){ sv = fmaf(hl[k], we[k], sv); su = fmaf(hl[k], we[32+k], su); }
  vep[node*32 + f] = sv;
  ue [node*32 + f] = su;

  const float* wc = c1w + f*66;
  float cv = c1b[f], cu = 0.f;
#pragma unroll
  for (int k = 0; k < 32; ++k){ cv = fmaf(hl[k], wc[k], cv); cu = fmaf(hl[k], wc[32+k], cu); }
  vcp[node*32 + f] = cv;
  uc [node*32 + f] = cu;
}

// ---------------- pair kernel (MFMA) + fused node-post ----------------------
// block=(i, b, chunk), 128 threads. Phases 0-2 as round 7. Then the LAST of
// the 3 chunk-blocks for (i,b) (device-scope atomic counter) runs the node
// MLP + x-update + next-layer LN/separable precompute (l<3) or output heads
// (l==3), wave0-only, shfl-based. Ping-pong buffers make same-launch
// write-next / read-current race-free; kernel boundary orders layers.
__global__ __launch_bounds__(128, 3) void k_pair(
    const float* __restrict__ xin, const float* __restrict__ xyz,
    const float* __restrict__ hln, const float* __restrict__ ue,
    const float* __restrict__ uc, const float* __restrict__ vep,
    const float* __restrict__ vcp,
    const float* __restrict__ e1w, const float* __restrict__ c1w,
    const unsigned short* __restrict__ e2wb, const unsigned short* __restrict__ c2wb,
    const float* __restrict__ e2b, const float* __restrict__ eiw,
    const float* __restrict__ eib,
    const float* __restrict__ c2b, const float* __restrict__ c3w,
    const float* __restrict__ c3b,
    const float* __restrict__ n1w, const float* __restrict__ n1b,
    const float* __restrict__ n2w, const float* __restrict__ n2b,
    const float* __restrict__ lnxg, const float* __restrict__ lnxb,
    const float* __restrict__ lnhg_n, const float* __restrict__ lnhb_n,
    const float* __restrict__ e1w_n, const float* __restrict__ e1b_n,
    const float* __restrict__ c1w_n, const float* __restrict__ c1b_n,
    float* __restrict__ hln_n, float* __restrict__ ue_n,
    float* __restrict__ uc_n, float* __restrict__ vep_n,
    float* __restrict__ vcp_n, float* __restrict__ xout,
    const float* __restrict__ how, const float* __restrict__ hob,
    const float* __restrict__ xow, const float* __restrict__ xob,
    float* __restrict__ dout, const int lastl,
    float* __restrict__ pm, float* __restrict__ pxc, int* __restrict__ cnt)
{
  __shared__ float s_geo[64][6];              // dfx,dfy,dfz,d2,d0,dist
  __shared__ unsigned short s_m1[64][40];     // bf16 m1, padded rows
  __shared__ unsigned short s_c1[64][40];
  __shared__ unsigned short s_we[32][40];
  __shared__ unsigned short s_wc[32][40];
  __shared__ int s_last;

  const int i = blockIdx.x, b = blockIdx.y, chunk = blockIdx.z;
  const int tid = threadIdx.x;
  const int base = b * NATOMS;

  // ---- phase 0 ----
  if (tid < 64){
    const int jj = tid;
    const int j = chunk*64 + jj;
    const float* xi_p = xin + (base + i)*3;
    const float* xj_p = xin + (base + j)*3;
    const float dfx = xi_p[0] - xj_p[0], dfy = xi_p[1] - xj_p[1], dfz = xi_p[2] - xj_p[2];
    const float d2 = dfx*dfx + dfy*dfy + dfz*dfz;
    const float dist = sqrtf(fmaxf(d2, 1e-12f));
    const float* x0i = xyz + (base + i)*4;
    const float* x0j = xyz + (base + j)*4;
    const float q0 = x0i[0]-x0j[0], q1 = x0i[1]-x0j[1], q2 = x0i[2]-x0j[2];
    const float d0 = sqrtf(fmaxf(q0*q0 + q1*q1 + q2*q2, 1e-12f));
    s_geo[jj][0] = dfx; s_geo[jj][1] = dfy; s_geo[jj][2] = dfz;
    s_geo[jj][3] = d2;  s_geo[jj][4] = d0;  s_geo[jj][5] = dist;
  } else {
    const int u = tid - 64;
    const short8* es = (const short8*)e2wb;
    const short8* cs = (const short8*)c2wb;
#pragma unroll
    for (int h = 0; h < 2; ++h){
      const int c = u + h*64;
      const int f = c >> 2, kq = c & 3;
      *(short8*)&s_we[f][kq*8] = es[c];
      *(short8*)&s_wc[f][kq*8] = cs[c];
    }
  }
  __syncthreads();

  // ---- phase 1: m1/c1 fp32 -> bf16 LDS ----
  {
    const int k = tid & 31, jg = tid >> 5;
    const float vpe = vep[(base + i)*32 + k];
    const float vpc = vcp[(base + i)*32 + k];
    const float we64 = e1w[k*66 + 64], we65 = e1w[k*66 + 65];
    const float wc64 = c1w[k*66 + 64], wc65 = c1w[k*66 + 65];
#pragma unroll
    for (int jj = jg; jj < 64; jj += 4){
      const float d2 = s_geo[jj][3], d0 = s_geo[jj][4];
      const int j = chunk*64 + jj;
      const float uev = ue[(size_t)(base + j)*32 + k];
      const float m1 = silu_f(fmaf(d2, we64, fmaf(d0, we65, vpe + uev)));
      s_m1[jj][k] = f2bf(m1);
      const float ucv = uc[(size_t)(base + j)*32 + k];
      const float c1 = silu_f(fmaf(d2, wc64, fmaf(d0, wc65, vpc + ucv)));
      s_c1[jj][k] = f2bf(c1);
    }
  }
  __syncthreads();

  // ---- phase 2 ----
  const int lane = tid & 63;
  const int n = lane & 15, quad = lane >> 4;

  if (tid < 64){
    // ======== edge wave ========
    short8 b0 = *(const short8*)&s_we[n][quad*8];
    short8 b1 = *(const short8*)&s_we[16 + n][quad*8];
    f32x4 acc0[4], acc1[4];
#pragma unroll
    for (int jt = 0; jt < 4; ++jt){
      short8 a = *(const short8*)&s_m1[jt*16 + n][quad*8];
      f32x4 z = {0.f, 0.f, 0.f, 0.f};
      acc0[jt] = __builtin_amdgcn_mfma_f32_16x16x32_bf16(a, b0, z, 0, 0, 0);
      acc1[jt] = __builtin_amdgcn_mfma_f32_16x16x32_bf16(a, b1, z, 0, 0, 0);
    }
    const float eb0 = e2b[n], eb1 = e2b[16 + n];
    const float ew0 = eiw[n], ew1 = eiw[16 + n];
    const float ebias = eib[0];
    float ma0 = 0.f, ma1 = 0.f;
#pragma unroll
    for (int jt = 0; jt < 4; ++jt){
      float m20[4], m21[4], g[4];
#pragma unroll
      for (int r = 0; r < 4; ++r){
        m20[r] = silu_f(acc0[jt][r] + eb0);
        m21[r] = silu_f(acc1[jt][r] + eb1);
        g[r] = m20[r]*ew0 + m21[r]*ew1;
      }
#pragma unroll
      for (int r = 0; r < 4; ++r){
        g[r] += __shfl_xor(g[r], 1);
        g[r] += __shfl_xor(g[r], 2);
        g[r] += __shfl_xor(g[r], 4);
        g[r] += __shfl_xor(g[r], 8);
      }
#pragma unroll
      for (int r = 0; r < 4; ++r){
        const int jglob = chunk*64 + jt*16 + quad*4 + r;
        const float e = (jglob == i) ? 0.0f : sigmoid_f(g[r] + ebias);
        ma0 = fmaf(e, m20[r], ma0);
        ma1 = fmaf(e, m21[r], ma1);
      }
    }
    ma0 += __shfl_xor(ma0, 16); ma0 += __shfl_xor(ma0, 32);
    ma1 += __shfl_xor(ma1, 16); ma1 += __shfl_xor(ma1, 32);
    if (lane < 16){
      float* o = pm + ((size_t)(base + i)*3 + chunk)*32;
      o[lane] = ma0;
      o[16 + lane] = ma1;
    }
  } else {
    // ======== coordinate wave ========
    short8 b0 = *(const short8*)&s_wc[n][quad*8];
    short8 b1 = *(const short8*)&s_wc[16 + n][quad*8];
    f32x4 acc0[4], acc1[4];
#pragma unroll
    for (int jt = 0; jt < 4; ++jt){
      short8 a = *(const short8*)&s_c1[jt*16 + n][quad*8];
      f32x4 z = {0.f, 0.f, 0.f, 0.f};
      acc0[jt] = __builtin_amdgcn_mfma_f32_16x16x32_bf16(a, b0, z, 0, 0, 0);
      acc1[jt] = __builtin_amdgcn_mfma_f32_16x16x32_bf16(a, b1, z, 0, 0, 0);
    }
    const float cb0 = c2b[n], cb1 = c2b[16 + n];
    const float cw0 = c3w[n], cw1 = c3w[16 + n];
    const float cbias = c3b[0];
    float px = 0.f, py = 0.f, pz = 0.f;
#pragma unroll
    for (int jt = 0; jt < 4; ++jt){
      float g[4];
#pragma unroll
      for (int r = 0; r < 4; ++r){
        g[r] = silu_f(acc0[jt][r] + cb0)*cw0 + silu_f(acc1[jt][r] + cb1)*cw1;
      }
#pragma unroll
      for (int r = 0; r < 4; ++r){
        g[r] += __shfl_xor(g[r], 1);
        g[r] += __shfl_xor(g[r], 2);
        g[r] += __shfl_xor(g[r], 4);
        g[r] += __shfl_xor(g[r], 8);
      }
#pragma unroll
      for (int r = 0; r < 4; ++r){
        const int jj = jt*16 + quad*4 + r;
        const float s = (g[r] + cbias) * fast_rcp(s_geo[jj][5] + 1.0f);
        px = fmaf(s, s_geo[jj][0], px);
        py = fmaf(s, s_geo[jj][1], py);
        pz = fmaf(s, s_geo[jj][2], pz);
      }
    }
    px += __shfl_xor(px, 16); px += __shfl_xor(px, 32);
    py += __shfl_xor(py, 16); py += __shfl_xor(py, 32);
    pz += __shfl_xor(pz, 16); pz += __shfl_xor(pz, 32);
    if (lane == 0){
      float* o = pxc + ((size_t)(base + i)*3 + chunk)*3;
      o[0] = px; o[1] = py; o[2] = pz;
    }
  }

  // ---- last-chunk-finishes-node protocol ----
  __threadfence();                       // release pm/pxc (device scope)
  if (tid == 0){
    const int old = atomicAdd(&cnt[base + i], 1);
    s_last = (old == 2) ? 1 : 0;
  }
  __syncthreads();                       // all 128 threads alive here
  if (!s_last) return;
  if (tid >= 64) return;                 // post on wave0 only
  __threadfence();                       // acquire other chunks' partials

  const int f = tid & 31;                // lanes 32-63 mirror 0-31 (benign)
  const int node = base + i;

  const float* pmn = pm + (size_t)node*96;
  const float mgf = pmn[f] + pmn[32 + f] + pmn[64 + f];
  const float hlf = hln[node*32 + f];

  // node1: a = n1b[f] + hl . w1[0:32] + mg . w1[32:64]   (shfl broadcasts)
  float a = n1b[f];
  const float* w1 = n1w + f*64;
#pragma unroll
  for (int k = 0; k < 32; ++k) a = fmaf(__shfl(hlf, k, 64), w1[k], a);
#pragma unroll
  for (int k = 0; k < 32; ++k) a = fmaf(__shfl(mgf, k, 64), w1[32 + k], a);
  const float n1v = silu_f(a);
  float o = n2b[f];
  const float* w2 = n2w + f*32;
#pragma unroll
  for (int k = 0; k < 32; ++k) o = fmaf(__shfl(n1v, k, 64), w2[k], o);
  const float ho = hlf + o;

  // x update: xn = LN(x_i) + sum of pxc partials
  float xn0, xn1, xn2;
  {
    const float* xr = xin + node*3;
    const float x0 = xr[0], x1 = xr[1], x2 = xr[2];
    const float mx = (x0 + x1 + x2) * (1.0f/3.0f);
    const float v0 = x0-mx, v1 = x1-mx, v2 = x2-mx;
    const float r = rsqrtf((v0*v0 + v1*v1 + v2*v2)*(1.0f/3.0f) + 1e-5f);
    const float* pc = pxc + (size_t)node*9;
    xn0 = fmaf(v0*r, lnxg[0], lnxb[0]) + pc[0] + pc[3] + pc[6];
    xn1 = fmaf(v1*r, lnxg[1], lnxb[1]) + pc[1] + pc[4] + pc[7];
    xn2 = fmaf(v2*r, lnxg[2], lnxb[2]) + pc[2] + pc[5] + pc[8];
  }

  if (!lastl){
    if (tid == 0){
      float* xo = xout + node*3;
      xo[0] = xn0; xo[1] = xn1; xo[2] = xn2;
    }
    // LN(ho) across 32 lanes (butterfly)
    float s = ho;
    s += __shfl_xor(s, 1); s += __shfl_xor(s, 2); s += __shfl_xor(s, 4);
    s += __shfl_xor(s, 8); s += __shfl_xor(s, 16);
    const float m = s * (1.0f/32.0f);
    const float d = ho - m;
    float vv = d*d;
    vv += __shfl_xor(vv, 1); vv += __shfl_xor(vv, 2); vv += __shfl_xor(vv, 4);
    vv += __shfl_xor(vv, 8); vv += __shfl_xor(vv, 16);
    const float r = rsqrtf(vv*(1.0f/32.0f) + 1e-5f);
    const float hl = fmaf(d*r, lnhg_n[f], lnhb_n[f]);
    if (tid < 32) hln_n[node*32 + f] = hl;

    const float* we = e1w_n + f*66;
    const float* wc = c1w_n + f*66;
    float sv = e1b_n[f], su = 0.f, cv = c1b_n[f], cu = 0.f;
#pragma unroll
    for (int k = 0; k < 32; ++k){
      const float tkk = __shfl(hl, k, 64);
      sv = fmaf(tkk, we[k], sv);
      su = fmaf(tkk, we[32 + k], su);
      cv = fmaf(tkk, wc[k], cv);
      cu = fmaf(tkk, wc[32 + k], cu);
    }
    if (tid < 32){
      vep_n[node*32 + f] = sv;
      ue_n [node*32 + f] = su;
      vcp_n[node*32 + f] = cv;
      uc_n [node*32 + f] = cu;
    }
  } else {
    // output heads directly
    float hh = how[f] * ho;
    hh += __shfl_xor(hh, 1); hh += __shfl_xor(hh, 2); hh += __shfl_xor(hh, 4);
    hh += __shfl_xor(hh, 8); hh += __shfl_xor(hh, 16);
    if (tid == 0) dout[node*4 + 3] = hh + hob[0];
    if (tid < 3){
      const int c = tid;
      float oo = xob[c];
      oo = fmaf(xn0, xow[c*3 + 0], oo);
      oo = fmaf(xn1, xow[c*3 + 1], oo);
      oo = fmaf(xn2, xow[c*3 + 2], oo);
      dout[node*4 + c] = oo - xyz[node*4 + c];
    }
  }
  if (tid == 0) cnt[node] = 0;           // re-arm for next layer (ordered by
                                         // kernel boundary)
}

extern "C" void kernel_launch(void* const* d_in, const int* in_sizes, int n_in,
                              void* d_out, int out_size, void* d_ws, size_t ws_size,
                              hipStream_t stream)
{
  const float* xyz      = (const float*)d_in[0];
  const float* pdf      = (const float*)d_in[1];
  const float* t        = (const float*)d_in[2];
  const float* emb_in_w = (const float*)d_in[3];
  const float* emb_in_b = (const float*)d_in[4];
  const float* emb_out_w= (const float*)d_in[5];
  const float* emb_out_b= (const float*)d_in[6];
  const float* x_out_w  = (const float*)d_in[7];
  const float* x_out_b  = (const float*)d_in[8];
  const float* pdf_w    = (const float*)d_in[9];
  const float* pdf_b    = (const float*)d_in[10];
  const float* g1w      = (const float*)d_in[11];
  const float* g1b      = (const float*)d_in[12];
  const float* g2w      = (const float*)d_in[13];
  const float* g2b      = (const float*)d_in[14];
  const float* g3w      = (const float*)d_in[15];
  const float* g3b      = (const float*)d_in[16];
  const float* gamma0   = (const float*)d_in[17];
  const float* gamma1   = (const float*)d_in[18];
  const float* lnhg     = (const float*)d_in[19];
  const float* lnhb     = (const float*)d_in[20];
  const float* lnxg     = (const float*)d_in[21];
  const float* lnxb     = (const float*)d_in[22];
  const float* e1w      = (const float*)d_in[23];
  const float* e1b      = (const float*)d_in[24];
  const float* e2w      = (const float*)d_in[25];
  const float* e2b      = (const float*)d_in[26];
  const float* eiw      = (const float*)d_in[27];
  const float* eib      = (const float*)d_in[28];
  const float* n1w      = (const float*)d_in[29];
  const float* n1b      = (const float*)d_in[30];
  const float* n2w      = (const float*)d_in[31];
  const float* n2b      = (const float*)d_in[32];
  const float* c1w      = (const float*)d_in[33];
  const float* c1b      = (const float*)d_in[34];
  const float* c2w      = (const float*)d_in[35];
  const float* c2b      = (const float*)d_in[36];
  const float* c3w      = (const float*)d_in[37];
  const float* c3b      = (const float*)d_in[38];

  const int NTOT = BATCH*NATOMS;          // 1536 nodes
  float* ws   = (float*)d_ws;
  float* temb = ws;                        // 8
  float* pdfe = ws + 8;                    // 80 (pad to 96)
  unsigned short* e2wb = (unsigned short*)(ws + 96);   // 4096 ushort
  unsigned short* c2wb = e2wb + 4096;                  // 4096 ushort
  float* p0   = ws + 96 + 4096;            // (8192 ushort = 4096 floats)
  float* xbA  = p0;                float* xbB  = xbA + NTOT*3;
  float* hlnA = xbB  + NTOT*3;     float* hlnB = hlnA + NTOT*32;
  float* ueA  = hlnB + NTOT*32;    float* ueB  = ueA  + NTOT*32;
  float* ucA  = ueB  + NTOT*32;    float* ucB  = ucA  + NTOT*32;
  float* vepA = ucB  + NTOT*32;    float* vepB = vepA + NTOT*32;
  float* vcpA = vepB + NTOT*32;    float* vcpB = vcpA + NTOT*32;
  float* pm   = vcpB + NTOT*32;            // 1536*96
  float* pxc  = pm   + NTOT*96;            // 1536*9
  int*   cnt  = (int*)(pxc + NTOT*9);      // 1536 ints

  float* xb[2]  = {xbA,  xbB};
  float* hlnP[2]= {hlnA, hlnB};
  float* ueP[2] = {ueA,  ueB};
  float* ucP[2] = {ucA,  ucB};
  float* vepP[2]= {vepA, vepB};
  float* vcpP[2]= {vcpA, vcpB};

  k_prelude<<<104, 256, 0, stream>>>(pdf, t, pdf_w, pdf_b,
      g1w, g1b, g2w, g2b, g3w, g3b, gamma0, gamma1,
      e2w, c2w, e2wb, c2wb, temb, pdfe);
  k_embed_node<<<NTOT/8, 256, 0, stream>>>(
      xyz, temb, pdfe, emb_in_w, emb_in_b,
      lnhg, lnhb, e1w, e1b, c1w, c1b,
      xbA, hlnA, ueA, ucA, vepA, vcpA, cnt);

  for (int l = 0; l < 4; ++l){
    const int p = l & 1;
    const int nl = (l < 3) ? (l + 1) : 3;  // next-layer weights (unused l==3)
    k_pair<<<dim3(NATOMS, BATCH, 3), 128, 0, stream>>>(
        xb[p], xyz, hlnP[p], ueP[p], ucP[p], vepP[p], vcpP[p],
        e1w + l*2112, c1w + l*2112,
        e2wb + l*1024, c2wb + l*1024,
        e2b + l*32, eiw + l*32, eib + l,
        c2b + l*32, c3w + l*32, c3b + l,
        n1w + l*2048, n1b + l*32, n2w + l*1024, n2b + l*32,
        lnxg + l*3, lnxb + l*3,
        lnhg + nl*32, lnhb + nl*32,
        e1w + nl*2112, e1b + nl*32, c1w + nl*2112, c1b + nl*32,
        hlnP[1-p], ueP[1-p], ucP[1-p], vepP[1-p], vcpP[1-p], xb[1-p],
        emb_out_w, emb_out_b, x_out_w, x_out_b,
        (float*)d_out, (l == 3) ? 1 : 0,
        pm, pxc, cnt);
  }
}

// Round 9
// 286.552 us; speedup vs baseline: 3.2314x; 3.2314x over previous
//
#include <hip/hip_runtime.h>
#include <hip/hip_bf16.h>
#include <math.h>

#define BATCH 8
#define NATOMS 192
#define HF 32

using short8 = __attribute__((ext_vector_type(8))) short;
using f32x4  = __attribute__((ext_vector_type(4))) float;

__device__ __forceinline__ float fast_rcp(float x){ return __builtin_amdgcn_rcpf(x); }
__device__ __forceinline__ float sigmoid_f(float x){ return fast_rcp(1.0f+__expf(-x)); }
__device__ __forceinline__ float silu_f(float x){ return x*fast_rcp(1.0f+__expf(-x)); }
__device__ __forceinline__ float softplus_f(float x){ return fmaxf(x,0.0f)+log1pf(expf(-fabsf(x))); }
__device__ __forceinline__ unsigned short f2bf(float x){
  __hip_bfloat16 h = __float2bfloat16(x);
  return __builtin_bit_cast(unsigned short, h);
}

__device__ __forceinline__ float wave_sum(float v){
  v += __shfl_xor(v, 1);
  v += __shfl_xor(v, 2);
  v += __shfl_xor(v, 4);
  v += __shfl_xor(v, 8);
  v += __shfl_xor(v, 16);
  v += __shfl_xor(v, 32);
  return v;
}

// ------ prelude: 0..79 pdf dot (b,o); 80..87 gamma(b); 88..103 bf16 wprep ---
__global__ __launch_bounds__(256) void k_prelude(
    const float* __restrict__ pdf, const float* __restrict__ t,
    const float* __restrict__ pdf_w, const float* __restrict__ pdf_b,
    const float* __restrict__ g1w, const float* __restrict__ g1b,
    const float* __restrict__ g2w, const float* __restrict__ g2b,
    const float* __restrict__ g3w, const float* __restrict__ g3b,
    const float* __restrict__ gamma0, const float* __restrict__ gamma1,
    const float* __restrict__ e2w, const float* __restrict__ c2w,
    unsigned short* __restrict__ e2wb, unsigned short* __restrict__ c2wb,
    float* __restrict__ temb, float* __restrict__ pdfe)
{
  __shared__ float lds[4];
  const int bx = blockIdx.x, tid = threadIdx.x;
  const int wv = tid >> 6, ln = tid & 63;

  if (bx >= 88){
    const int g = (bx - 88)*256 + tid;   // 4096 elements each
    e2wb[g] = f2bf(e2w[g]);
    c2wb[g] = f2bf(c2w[g]);
    return;
  }
  if (bx < 80){
    const int b = bx / 10, o = bx % 10;
    const float* pb = pdf + b*3000;
    const float* wb = pdf_w + o*3000;
    float p = 0.f;
    for (int k = tid; k < 3000; k += 256) p = fmaf(pb[k], wb[k], p);
    p = wave_sum(p);
    if (ln == 0) lds[wv] = p;
    __syncthreads();
    if (tid == 0) pdfe[b*10 + o] = lds[0] + lds[1] + lds[2] + lds[3] + pdf_b[o];
    return;
  }
  const int b = bx - 80;
  const float w1 = softplus_f(g1w[0]);
  const float b1 = g1b[0];
  const float tn = t[b] * (1.0f/1000.0f);
  const float l1_0 = b1;
  const float l1_1 = w1 + b1;
  const float l1_t = fmaf(w1, tn, b1);
  float a0 = 0.f, a1 = 0.f, at = 0.f;
  for (int k = tid; k < 1024; k += 256){
    float w2 = softplus_f(g2w[k]);
    float bb = g2b[k];
    float w3 = softplus_f(g3w[k]);
    a0 += sigmoid_f(fmaf(w2, l1_0, bb)) * w3;
    a1 += sigmoid_f(fmaf(w2, l1_1, bb)) * w3;
    at += sigmoid_f(fmaf(w2, l1_t, bb)) * w3;
  }
  float sums[3]; float vals[3] = {a0, a1, at};
  for (int r = 0; r < 3; ++r){
    float v = wave_sum(vals[r]);
    __syncthreads();
    if (ln == 0) lds[wv] = v;
    __syncthreads();
    sums[r] = lds[0] + lds[1] + lds[2] + lds[3];
  }
  if (tid == 0){
    const float b3 = g3b[0];
    const float g0 = l1_0 + sums[0] + b3;
    const float g1v = l1_1 + sums[1] + b3;
    const float gt = l1_t + sums[2] + b3;
    temb[b] = gamma0[0] + (gamma1[0] - gamma0[0]) * (gt - g0) / (g1v - g0);
  }
}

// ---- embed + layer-0 node precompute fused (h0 lives only in LDS) ----------
__global__ __launch_bounds__(256) void k_embed_node(
    const float* __restrict__ xyz, const float* __restrict__ temb,
    const float* __restrict__ pdfe, const float* __restrict__ wi,
    const float* __restrict__ bi,
    const float* __restrict__ lnhg, const float* __restrict__ lnhb,
    const float* __restrict__ e1w, const float* __restrict__ e1b,
    const float* __restrict__ c1w, const float* __restrict__ c1b,
    float* __restrict__ x, float* __restrict__ hln,
    float* __restrict__ ue, float* __restrict__ uc,
    float* __restrict__ vep, float* __restrict__ vcp)
{
  __shared__ float s_h[8][33];
  const int tid = threadIdx.x;
  const int il = tid >> 5, f = tid & 31;
  const int node = blockIdx.x*8 + il;
  const int b = node / NATOMS;

  {
    const float sp = xyz[node*4 + 3];
    const float* w = wi + f*12;
    float a = bi[f];
    a = fmaf(sp, w[0], a);
    a = fmaf(temb[b], w[1], a);
    const float* pe = pdfe + b*10;
#pragma unroll
    for (int p = 0; p < 10; ++p) a = fmaf(pe[p], w[2+p], a);
    s_h[il][f] = a;
  }
  if (f < 3) x[node*3 + f] = xyz[node*4 + f];
  __syncthreads();

  float hl[32];
  float m = 0.f;
#pragma unroll
  for (int k = 0; k < 32; ++k){ hl[k] = s_h[il][k]; m += hl[k]; }
  m *= (1.0f/32.0f);
  float v = 0.f;
#pragma unroll
  for (int k = 0; k < 32; ++k){ float d = hl[k]-m; v = fmaf(d, d, v); }
  float r = rsqrtf(v*(1.0f/32.0f) + 1e-5f);
#pragma unroll
  for (int k = 0; k < 32; ++k) hl[k] = fmaf((hl[k]-m)*r, lnhg[k], lnhb[k]);
  hln[node*32 + f] = hl[f];

  const float* we = e1w + f*66;
  float sv = e1b[f], su = 0.f;
#pragma unroll
  for (int k = 0; k < 32; ++k){ sv = fmaf(hl[k], we[k], sv); su = fmaf(hl[k], we[32+k], su); }
  vep[node*32 + f] = sv;
  ue [node*32 + f] = su;

  const float* wc = c1w + f*66;
  float cv = c1b[f], cu = 0.f;
#pragma unroll
  for (int k = 0; k < 32; ++k){ cv = fmaf(hl[k], wc[k], cv); cu = fmaf(hl[k], wc[32+k], cu); }
  vcp[node*32 + f] = cv;
  uc [node*32 + f] = cu;
}

// ---------------- pair kernel (MFMA), whole node per block ------------------
// block=(i,b), 128 threads. Loops 3 chunks of 64 j's: geo -> m1/c1 bf16 LDS
// -> MFMA edg2/cor2 + epilogue, accumulating m_agg (wave0 regs) and xc
// (wave1 regs). Then node-post runs in wave0 of the SAME block: no atomics,
// no fences (round-8 lesson: __threadfence = cross-XCD L2 flush, 10x
// regression). Ping-pong buffers + kernel boundary order the layers.
__global__ __launch_bounds__(128, 3) void k_pair(
    const float* __restrict__ xin, const float* __restrict__ xyz,
    const float* __restrict__ hln, const float* __restrict__ ue,
    const float* __restrict__ uc, const float* __restrict__ vep,
    const float* __restrict__ vcp,
    const float* __restrict__ e1w, const float* __restrict__ c1w,
    const unsigned short* __restrict__ e2wb, const unsigned short* __restrict__ c2wb,
    const float* __restrict__ e2b, const float* __restrict__ eiw,
    const float* __restrict__ eib,
    const float* __restrict__ c2b, const float* __restrict__ c3w,
    const float* __restrict__ c3b,
    const float* __restrict__ n1w, const float* __restrict__ n1b,
    const float* __restrict__ n2w, const float* __restrict__ n2b,
    const float* __restrict__ lnxg, const float* __restrict__ lnxb,
    const float* __restrict__ lnhg_n, const float* __restrict__ lnhb_n,
    const float* __restrict__ e1w_n, const float* __restrict__ e1b_n,
    const float* __restrict__ c1w_n, const float* __restrict__ c1b_n,
    float* __restrict__ hln_n, float* __restrict__ ue_n,
    float* __restrict__ uc_n, float* __restrict__ vep_n,
    float* __restrict__ vcp_n, float* __restrict__ xout,
    const float* __restrict__ how, const float* __restrict__ hob,
    const float* __restrict__ xow, const float* __restrict__ xob,
    float* __restrict__ dout, const int lastl)
{
  __shared__ float s_geo[64][6];              // dfx,dfy,dfz,d2,d0,dist
  __shared__ unsigned short s_m1[64][40];     // bf16 m1, padded rows
  __shared__ unsigned short s_c1[64][40];
  __shared__ unsigned short s_we[32][40];
  __shared__ unsigned short s_wc[32][40];
  __shared__ float s_xc[3];

  const int i = blockIdx.x, b = blockIdx.y;
  const int tid = threadIdx.x;
  const int base = b * NATOMS;
  const int node = base + i;
  const int lane = tid & 63;
  const int n = lane & 15, quad = lane >> 4;

  // stage bf16 weights once (all 128 threads; 128 short8 chunks each array)
  {
    const short8* es = (const short8*)e2wb;
    const short8* cs = (const short8*)c2wb;
    const int f = tid >> 2, kq = tid & 3;
    *(short8*)&s_we[f][kq*8] = es[tid];
    *(short8*)&s_wc[f][kq*8] = cs[tid];
  }

  // wave-uniform i-side loop invariants for phase 1
  const int kk = tid & 31, jg = tid >> 5;     // phase-1 roles
  const float vpe = vep[node*32 + kk];
  const float vpc = vcp[node*32 + kk];
  const float we64 = e1w[kk*66 + 64], we65 = e1w[kk*66 + 65];
  const float wc64 = c1w[kk*66 + 64], wc65 = c1w[kk*66 + 65];

  // epilogue constants
  const float eb0 = e2b[n], eb1 = e2b[16 + n];
  const float ew0 = eiw[n], ew1 = eiw[16 + n];
  const float ebias = eib[0];
  const float cb0 = c2b[n], cb1 = c2b[16 + n];
  const float cw0 = c3w[n], cw1 = c3w[16 + n];
  const float cbias = c3b[0];

  float ma0 = 0.f, ma1 = 0.f;                 // edge-wave accumulators
  float px = 0.f, py = 0.f, pz = 0.f;         // cor-wave accumulators

  for (int chunk = 0; chunk < 3; ++chunk){
    // ---- geo for this chunk's 64 j's ----
    if (tid < 64){
      const int jj = tid;
      const int j = chunk*64 + jj;
      const float* xi_p = xin + node*3;
      const float* xj_p = xin + (base + j)*3;
      const float dfx = xi_p[0] - xj_p[0], dfy = xi_p[1] - xj_p[1], dfz = xi_p[2] - xj_p[2];
      const float d2 = dfx*dfx + dfy*dfy + dfz*dfz;
      const float dist = sqrtf(fmaxf(d2, 1e-12f));
      const float* x0i = xyz + node*4;
      const float* x0j = xyz + (base + j)*4;
      const float q0 = x0i[0]-x0j[0], q1 = x0i[1]-x0j[1], q2 = x0i[2]-x0j[2];
      const float d0 = sqrtf(fmaxf(q0*q0 + q1*q1 + q2*q2, 1e-12f));
      s_geo[jj][0] = dfx; s_geo[jj][1] = dfy; s_geo[jj][2] = dfz;
      s_geo[jj][3] = d2;  s_geo[jj][4] = d0;  s_geo[jj][5] = dist;
    }
    __syncthreads();

    // ---- phase 1: m1/c1 fp32 -> bf16 LDS ----
#pragma unroll
    for (int jj = jg; jj < 64; jj += 4){
      const float d2 = s_geo[jj][3], d0 = s_geo[jj][4];
      const int j = chunk*64 + jj;
      const float uev = ue[(size_t)(base + j)*32 + kk];
      const float m1 = silu_f(fmaf(d2, we64, fmaf(d0, we65, vpe + uev)));
      s_m1[jj][kk] = f2bf(m1);
      const float ucv = uc[(size_t)(base + j)*32 + kk];
      const float c1 = silu_f(fmaf(d2, wc64, fmaf(d0, wc65, vpc + ucv)));
      s_c1[jj][kk] = f2bf(c1);
    }
    __syncthreads();

    // ---- phase 2 ----
    if (tid < 64){
      // edge wave
      short8 b0 = *(const short8*)&s_we[n][quad*8];
      short8 b1 = *(const short8*)&s_we[16 + n][quad*8];
#pragma unroll
      for (int jt = 0; jt < 4; ++jt){
        short8 a = *(const short8*)&s_m1[jt*16 + n][quad*8];
        f32x4 z = {0.f, 0.f, 0.f, 0.f};
        f32x4 acc0 = __builtin_amdgcn_mfma_f32_16x16x32_bf16(a, b0, z, 0, 0, 0);
        f32x4 acc1 = __builtin_amdgcn_mfma_f32_16x16x32_bf16(a, b1, z, 0, 0, 0);
        float m20[4], m21[4], g[4];
#pragma unroll
        for (int r = 0; r < 4; ++r){
          m20[r] = silu_f(acc0[r] + eb0);
          m21[r] = silu_f(acc1[r] + eb1);
          g[r] = m20[r]*ew0 + m21[r]*ew1;
        }
#pragma unroll
        for (int r = 0; r < 4; ++r){
          g[r] += __shfl_xor(g[r], 1);
          g[r] += __shfl_xor(g[r], 2);
          g[r] += __shfl_xor(g[r], 4);
          g[r] += __shfl_xor(g[r], 8);
        }
#pragma unroll
        for (int r = 0; r < 4; ++r){
          const int jglob = chunk*64 + jt*16 + quad*4 + r;
          const float e = (jglob == i) ? 0.0f : sigmoid_f(g[r] + ebias);
          ma0 = fmaf(e, m20[r], ma0);
          ma1 = fmaf(e, m21[r], ma1);
        }
      }
    } else {
      // coordinate wave
      short8 b0 = *(const short8*)&s_wc[n][quad*8];
      short8 b1 = *(const short8*)&s_wc[16 + n][quad*8];
#pragma unroll
      for (int jt = 0; jt < 4; ++jt){
        short8 a = *(const short8*)&s_c1[jt*16 + n][quad*8];
        f32x4 z = {0.f, 0.f, 0.f, 0.f};
        f32x4 acc0 = __builtin_amdgcn_mfma_f32_16x16x32_bf16(a, b0, z, 0, 0, 0);
        f32x4 acc1 = __builtin_amdgcn_mfma_f32_16x16x32_bf16(a, b1, z, 0, 0, 0);
        float g[4];
#pragma unroll
        for (int r = 0; r < 4; ++r){
          g[r] = silu_f(acc0[r] + cb0)*cw0 + silu_f(acc1[r] + cb1)*cw1;
        }
#pragma unroll
        for (int r = 0; r < 4; ++r){
          g[r] += __shfl_xor(g[r], 1);
          g[r] += __shfl_xor(g[r], 2);
          g[r] += __shfl_xor(g[r], 4);
          g[r] += __shfl_xor(g[r], 8);
        }
#pragma unroll
        for (int r = 0; r < 4; ++r){
          const int jj = jt*16 + quad*4 + r;
          const float s = (g[r] + cbias) * fast_rcp(s_geo[jj][5] + 1.0f);
          px = fmaf(s, s_geo[jj][0], px);
          py = fmaf(s, s_geo[jj][1], py);
          pz = fmaf(s, s_geo[jj][2], pz);
        }
      }
    }
    __syncthreads();   // protect s_geo/s_m1/s_c1 for next chunk
  }

  // final reductions
  if (tid < 64){
    ma0 += __shfl_xor(ma0, 16); ma0 += __shfl_xor(ma0, 32);
    ma1 += __shfl_xor(ma1, 16); ma1 += __shfl_xor(ma1, 32);
  } else {
    px += __shfl_xor(px, 16); px += __shfl_xor(px, 32);
    py += __shfl_xor(py, 16); py += __shfl_xor(py, 32);
    pz += __shfl_xor(pz, 16); pz += __shfl_xor(pz, 32);
    if (lane == 0){ s_xc[0] = px; s_xc[1] = py; s_xc[2] = pz; }
  }
  __syncthreads();
  if (tid >= 64) return;                 // post on wave0 only

  const int f = tid & 31;                // lanes 32-63 mirror 0-31 (benign)
  const float mgf = (tid & 16) ? ma1 : ma0;   // m_agg[f] (reduced, lane n=f&15)
  const float hlf = hln[node*32 + f];

  // node MLP via shfl broadcasts
  float a = n1b[f];
  const float* w1 = n1w + f*64;
#pragma unroll
  for (int k = 0; k < 32; ++k) a = fmaf(__shfl(hlf, k, 64), w1[k], a);
#pragma unroll
  for (int k = 0; k < 32; ++k) a = fmaf(__shfl(mgf, k, 64), w1[32 + k], a);
  const float n1v = silu_f(a);
  float o = n2b[f];
  const float* w2 = n2w + f*32;
#pragma unroll
  for (int k = 0; k < 32; ++k) o = fmaf(__shfl(n1v, k, 64), w2[k], o);
  const float ho = hlf + o;

  // x update: xn = LN(x_i) + xc
  float xn0, xn1, xn2;
  {
    const float* xr = xin + node*3;
    const float x0 = xr[0], x1 = xr[1], x2 = xr[2];
    const float mx = (x0 + x1 + x2) * (1.0f/3.0f);
    const float v0 = x0-mx, v1 = x1-mx, v2 = x2-mx;
    const float r = rsqrtf((v0*v0 + v1*v1 + v2*v2)*(1.0f/3.0f) + 1e-5f);
    xn0 = fmaf(v0*r, lnxg[0], lnxb[0]) + s_xc[0];
    xn1 = fmaf(v1*r, lnxg[1], lnxb[1]) + s_xc[1];
    xn2 = fmaf(v2*r, lnxg[2], lnxb[2]) + s_xc[2];
  }

  if (!lastl){
    if (tid == 0){
      float* xo = xout + node*3;
      xo[0] = xn0; xo[1] = xn1; xo[2] = xn2;
    }
    // LN(ho) across 32 lanes (butterfly; lanes 32-63 mirror)
    float s = ho;
    s += __shfl_xor(s, 1); s += __shfl_xor(s, 2); s += __shfl_xor(s, 4);
    s += __shfl_xor(s, 8); s += __shfl_xor(s, 16);
    const float m = s * (1.0f/32.0f);
    const float d = ho - m;
    float vv = d*d;
    vv += __shfl_xor(vv, 1); vv += __shfl_xor(vv, 2); vv += __shfl_xor(vv, 4);
    vv += __shfl_xor(vv, 8); vv += __shfl_xor(vv, 16);
    const float r = rsqrtf(vv*(1.0f/32.0f) + 1e-5f);
    const float hl = fmaf(d*r, lnhg_n[f], lnhb_n[f]);
    if (tid < 32) hln_n[node*32 + f] = hl;

    const float* we = e1w_n + f*66;
    const float* wc = c1w_n + f*66;
    float sv = e1b_n[f], su = 0.f, cv = c1b_n[f], cu = 0.f;
#pragma unroll
    for (int k = 0; k < 32; ++k){
      const float tkk = __shfl(hl, k, 64);
      sv = fmaf(tkk, we[k], sv);
      su = fmaf(tkk, we[32 + k], su);
      cv = fmaf(tkk, wc[k], cv);
      cu = fmaf(tkk, wc[32 + k], cu);
    }
    if (tid < 32){
      vep_n[node*32 + f] = sv;
      ue_n [node*32 + f] = su;
      vcp_n[node*32 + f] = cv;
      uc_n [node*32 + f] = cu;
    }
  } else {
    // output heads directly
    float hh = how[f] * ho;
    hh += __shfl_xor(hh, 1); hh += __shfl_xor(hh, 2); hh += __shfl_xor(hh, 4);
    hh += __shfl_xor(hh, 8); hh += __shfl_xor(hh, 16);
    if (tid == 0) dout[node*4 + 3] = hh + hob[0];
    if (tid < 3){
      const int c = tid;
      float oo = xob[c];
      oo = fmaf(xn0, xow[c*3 + 0], oo);
      oo = fmaf(xn1, xow[c*3 + 1], oo);
      oo = fmaf(xn2, xow[c*3 + 2], oo);
      dout[node*4 + c] = oo - xyz[node*4 + c];
    }
  }
}

extern "C" void kernel_launch(void* const* d_in, const int* in_sizes, int n_in,
                              void* d_out, int out_size, void* d_ws, size_t ws_size,
                              hipStream_t stream)
{
  const float* xyz      = (const float*)d_in[0];
  const float* pdf      = (const float*)d_in[1];
  const float* t        = (const float*)d_in[2];
  const float* emb_in_w = (const float*)d_in[3];
  const float* emb_in_b = (const float*)d_in[4];
  const float* emb_out_w= (const float*)d_in[5];
  const float* emb_out_b= (const float*)d_in[6];
  const float* x_out_w  = (const float*)d_in[7];
  const float* x_out_b  = (const float*)d_in[8];
  const float* pdf_w    = (const float*)d_in[9];
  const float* pdf_b    = (const float*)d_in[10];
  const float* g1w      = (const float*)d_in[11];
  const float* g1b      = (const float*)d_in[12];
  const float* g2w      = (const float*)d_in[13];
  const float* g2b      = (const float*)d_in[14];
  const float* g3w      = (const float*)d_in[15];
  const float* g3b      = (const float*)d_in[16];
  const float* gamma0   = (const float*)d_in[17];
  const float* gamma1   = (const float*)d_in[18];
  const float* lnhg     = (const float*)d_in[19];
  const float* lnhb     = (const float*)d_in[20];
  const float* lnxg     = (const float*)d_in[21];
  const float* lnxb     = (const float*)d_in[22];
  const float* e1w      = (const float*)d_in[23];
  const float* e1b      = (const float*)d_in[24];
  const float* e2w      = (const float*)d_in[25];
  const float* e2b      = (const float*)d_in[26];
  const float* eiw      = (const float*)d_in[27];
  const float* eib      = (const float*)d_in[28];
  const float* n1w      = (const float*)d_in[29];
  const float* n1b      = (const float*)d_in[30];
  const float* n2w      = (const float*)d_in[31];
  const float* n2b      = (const float*)d_in[32];
  const float* c1w      = (const float*)d_in[33];
  const float* c1b      = (const float*)d_in[34];
  const float* c2w      = (const float*)d_in[35];
  const float* c2b      = (const float*)d_in[36];
  const float* c3w      = (const float*)d_in[37];
  const float* c3b      = (const float*)d_in[38];

  const int NTOT = BATCH*NATOMS;          // 1536 nodes
  float* ws   = (float*)d_ws;
  float* temb = ws;                        // 8
  float* pdfe = ws + 8;                    // 80 (pad to 96)
  unsigned short* e2wb = (unsigned short*)(ws + 96);   // 4096 ushort
  unsigned short* c2wb = e2wb + 4096;                  // 4096 ushort
  float* p0   = ws + 96 + 4096;            // (8192 ushort = 4096 floats)
  float* xbA  = p0;                float* xbB  = xbA + NTOT*3;
  float* hlnA = xbB  + NTOT*3;     float* hlnB = hlnA + NTOT*32;
  float* ueA  = hlnB + NTOT*32;    float* ueB  = ueA  + NTOT*32;
  float* ucA  = ueB  + NTOT*32;    float* ucB  = ucA  + NTOT*32;
  float* vepA = ucB  + NTOT*32;    float* vepB = vepA + NTOT*32;
  float* vcpA = vepB + NTOT*32;    float* vcpB = vcpA + NTOT*32;

  float* xb[2]  = {xbA,  xbB};
  float* hlnP[2]= {hlnA, hlnB};
  float* ueP[2] = {ueA,  ueB};
  float* ucP[2] = {ucA,  ucB};
  float* vepP[2]= {vepA, vepB};
  float* vcpP[2]= {vcpA, vcpB};

  k_prelude<<<104, 256, 0, stream>>>(pdf, t, pdf_w, pdf_b,
      g1w, g1b, g2w, g2b, g3w, g3b, gamma0, gamma1,
      e2w, c2w, e2wb, c2wb, temb, pdfe);
  k_embed_node<<<NTOT/8, 256, 0, stream>>>(
      xyz, temb, pdfe, emb_in_w, emb_in_b,
      lnhg, lnhb, e1w, e1b, c1w, c1b,
      xbA, hlnA, ueA, ucA, vepA, vcpA);

  for (int l = 0; l < 4; ++l){
    const int p = l & 1;
    const int nl = (l < 3) ? (l + 1) : 3;  // next-layer weights (unused l==3)
    k_pair<<<dim3(NATOMS, BATCH), 128, 0, stream>>>(
        xb[p], xyz, hlnP[p], ueP[p], ucP[p], vepP[p], vcpP[p],
        e1w + l*2112, c1w + l*2112,
        e2wb + l*1024, c2wb + l*1024,
        e2b + l*32, eiw + l*32, eib + l,
        c2b + l*32, c3w + l*32, c3b + l,
        n1w + l*2048, n1b + l*32, n2w + l*1024, n2b + l*32,
        lnxg + l*3, lnxb + l*3,
        lnhg + nl*32, lnhb + nl*32,
        e1w + nl*2112, e1b + nl*32, c1w + nl*2112, c1b + nl*32,
        hlnP[1-p], ueP[1-p], ucP[1-p], vepP[1-p], vcpP[1-p], xb[1-p],
        emb_out_w, emb_out_b, x_out_w, x_out_b,
        (float*)d_out, (l == 3) ? 1 : 0);
  }
}

// Round 10
// 275.351 us; speedup vs baseline: 3.3629x; 1.0407x over previous
//
#include <hip/hip_runtime.h>
#include <hip/hip_bf16.h>
#include <math.h>

#define BATCH 8
#define NATOMS 192
#define HF 32

using short8 = __attribute__((ext_vector_type(8))) short;
using f32x4  = __attribute__((ext_vector_type(4))) float;

__device__ __forceinline__ float fast_rcp(float x){ return __builtin_amdgcn_rcpf(x); }
__device__ __forceinline__ float sigmoid_f(float x){ return fast_rcp(1.0f+__expf(-x)); }
__device__ __forceinline__ float silu_f(float x){ return x*fast_rcp(1.0f+__expf(-x)); }
__device__ __forceinline__ float softplus_f(float x){ return fmaxf(x,0.0f)+log1pf(expf(-fabsf(x))); }
__device__ __forceinline__ unsigned short f2bf(float x){
  __hip_bfloat16 h = __float2bfloat16(x);
  return __builtin_bit_cast(unsigned short, h);
}

__device__ __forceinline__ float wave_sum(float v){
  v += __shfl_xor(v, 1);
  v += __shfl_xor(v, 2);
  v += __shfl_xor(v, 4);
  v += __shfl_xor(v, 8);
  v += __shfl_xor(v, 16);
  v += __shfl_xor(v, 32);
  return v;
}

// ------ prelude: 0..79 pdf dot (b,o); 80..87 gamma(b); 88..103 bf16 wprep ---
__global__ __launch_bounds__(256) void k_prelude(
    const float* __restrict__ pdf, const float* __restrict__ t,
    const float* __restrict__ pdf_w, const float* __restrict__ pdf_b,
    const float* __restrict__ g1w, const float* __restrict__ g1b,
    const float* __restrict__ g2w, const float* __restrict__ g2b,
    const float* __restrict__ g3w, const float* __restrict__ g3b,
    const float* __restrict__ gamma0, const float* __restrict__ gamma1,
    const float* __restrict__ e2w, const float* __restrict__ c2w,
    unsigned short* __restrict__ e2wb, unsigned short* __restrict__ c2wb,
    float* __restrict__ temb, float* __restrict__ pdfe)
{
  __shared__ float lds[4];
  const int bx = blockIdx.x, tid = threadIdx.x;
  const int wv = tid >> 6, ln = tid & 63;

  if (bx >= 88){
    const int g = (bx - 88)*256 + tid;   // 4096 elements each
    e2wb[g] = f2bf(e2w[g]);
    c2wb[g] = f2bf(c2w[g]);
    return;
  }
  if (bx < 80){
    const int b = bx / 10, o = bx % 10;
    const float* pb = pdf + b*3000;
    const float* wb = pdf_w + o*3000;
    float p = 0.f;
    for (int k = tid; k < 3000; k += 256) p = fmaf(pb[k], wb[k], p);
    p = wave_sum(p);
    if (ln == 0) lds[wv] = p;
    __syncthreads();
    if (tid == 0) pdfe[b*10 + o] = lds[0] + lds[1] + lds[2] + lds[3] + pdf_b[o];
    return;
  }
  const int b = bx - 80;
  const float w1 = softplus_f(g1w[0]);
  const float b1 = g1b[0];
  const float tn = t[b] * (1.0f/1000.0f);
  const float l1_0 = b1;
  const float l1_1 = w1 + b1;
  const float l1_t = fmaf(w1, tn, b1);
  float a0 = 0.f, a1 = 0.f, at = 0.f;
  for (int k = tid; k < 1024; k += 256){
    float w2 = softplus_f(g2w[k]);
    float bb = g2b[k];
    float w3 = softplus_f(g3w[k]);
    a0 += sigmoid_f(fmaf(w2, l1_0, bb)) * w3;
    a1 += sigmoid_f(fmaf(w2, l1_1, bb)) * w3;
    at += sigmoid_f(fmaf(w2, l1_t, bb)) * w3;
  }
  float sums[3]; float vals[3] = {a0, a1, at};
  for (int r = 0; r < 3; ++r){
    float v = wave_sum(vals[r]);
    __syncthreads();
    if (ln == 0) lds[wv] = v;
    __syncthreads();
    sums[r] = lds[0] + lds[1] + lds[2] + lds[3];
  }
  if (tid == 0){
    const float b3 = g3b[0];
    const float g0 = l1_0 + sums[0] + b3;
    const float g1v = l1_1 + sums[1] + b3;
    const float gt = l1_t + sums[2] + b3;
    temb[b] = gamma0[0] + (gamma1[0] - gamma0[0]) * (gt - g0) / (g1v - g0);
  }
}

// ---- embed + layer-0 node precompute fused (h0 lives only in LDS) ----------
__global__ __launch_bounds__(256) void k_embed_node(
    const float* __restrict__ xyz, const float* __restrict__ temb,
    const float* __restrict__ pdfe, const float* __restrict__ wi,
    const float* __restrict__ bi,
    const float* __restrict__ lnhg, const float* __restrict__ lnhb,
    const float* __restrict__ e1w, const float* __restrict__ e1b,
    const float* __restrict__ c1w, const float* __restrict__ c1b,
    float* __restrict__ x, float* __restrict__ hln,
    float* __restrict__ ue, float* __restrict__ uc,
    float* __restrict__ vep, float* __restrict__ vcp)
{
  __shared__ float s_h[8][33];
  const int tid = threadIdx.x;
  const int il = tid >> 5, f = tid & 31;
  const int node = blockIdx.x*8 + il;
  const int b = node / NATOMS;

  {
    const float sp = xyz[node*4 + 3];
    const float* w = wi + f*12;
    float a = bi[f];
    a = fmaf(sp, w[0], a);
    a = fmaf(temb[b], w[1], a);
    const float* pe = pdfe + b*10;
#pragma unroll
    for (int p = 0; p < 10; ++p) a = fmaf(pe[p], w[2+p], a);
    s_h[il][f] = a;
  }
  if (f < 3) x[node*3 + f] = xyz[node*4 + f];
  __syncthreads();

  float hl[32];
  float m = 0.f;
#pragma unroll
  for (int k = 0; k < 32; ++k){ hl[k] = s_h[il][k]; m += hl[k]; }
  m *= (1.0f/32.0f);
  float v = 0.f;
#pragma unroll
  for (int k = 0; k < 32; ++k){ float d = hl[k]-m; v = fmaf(d, d, v); }
  float r = rsqrtf(v*(1.0f/32.0f) + 1e-5f);
#pragma unroll
  for (int k = 0; k < 32; ++k) hl[k] = fmaf((hl[k]-m)*r, lnhg[k], lnhb[k]);
  hln[node*32 + f] = hl[f];

  const float* we = e1w + f*66;
  float sv = e1b[f], su = 0.f;
#pragma unroll
  for (int k = 0; k < 32; ++k){ sv = fmaf(hl[k], we[k], sv); su = fmaf(hl[k], we[32+k], su); }
  vep[node*32 + f] = sv;
  ue [node*32 + f] = su;

  const float* wc = c1w + f*66;
  float cv = c1b[f], cu = 0.f;
#pragma unroll
  for (int k = 0; k < 32; ++k){ cv = fmaf(hl[k], wc[k], cv); cu = fmaf(hl[k], wc[32+k], cu); }
  vcp[node*32 + f] = cv;
  uc [node*32 + f] = cu;
}

// ---------------- pair kernel (MFMA), whole node per block, 6 waves ---------
// block=(i,b), 384 threads = 3 chunk-groups x (edge wave + cor wave).
// Group g owns j in [g*64, g*64+64): phase1 m1/c1 -> bf16 LDS, phase2 MFMA
// edg2/cor2 + epilogue. Per-group partials to s_pm/s_pxc (same summation
// order as R7 -> absmax unchanged). Node-post on wave0 of the same block.
// No atomics/fences (R8 lesson). 3 barriers total; 6 waves hide latency.
// Ping-pong buffers + kernel boundary order the layers.
__global__ __launch_bounds__(384, 2) void k_pair(
    const float* __restrict__ xin, const float* __restrict__ xyz,
    const float* __restrict__ hln, const float* __restrict__ ue,
    const float* __restrict__ uc, const float* __restrict__ vep,
    const float* __restrict__ vcp,
    const float* __restrict__ e1w, const float* __restrict__ c1w,
    const unsigned short* __restrict__ e2wb, const unsigned short* __restrict__ c2wb,
    const float* __restrict__ e2b, const float* __restrict__ eiw,
    const float* __restrict__ eib,
    const float* __restrict__ c2b, const float* __restrict__ c3w,
    const float* __restrict__ c3b,
    const float* __restrict__ n1w, const float* __restrict__ n1b,
    const float* __restrict__ n2w, const float* __restrict__ n2b,
    const float* __restrict__ lnxg, const float* __restrict__ lnxb,
    const float* __restrict__ lnhg_n, const float* __restrict__ lnhb_n,
    const float* __restrict__ e1w_n, const float* __restrict__ e1b_n,
    const float* __restrict__ c1w_n, const float* __restrict__ c1b_n,
    float* __restrict__ hln_n, float* __restrict__ ue_n,
    float* __restrict__ uc_n, float* __restrict__ vep_n,
    float* __restrict__ vcp_n, float* __restrict__ xout,
    const float* __restrict__ how, const float* __restrict__ hob,
    const float* __restrict__ xow, const float* __restrict__ xob,
    float* __restrict__ dout, const int lastl)
{
  __shared__ float s_geo[NATOMS][6];            // dfx,dfy,dfz,d2,d0,dist
  __shared__ unsigned short s_m1[NATOMS][40];   // bf16 m1, padded rows
  __shared__ unsigned short s_c1[NATOMS][40];
  __shared__ unsigned short s_we[32][40];
  __shared__ unsigned short s_wc[32][40];
  __shared__ float s_pm[3][32];
  __shared__ float s_pxc[3][3];

  const int i = blockIdx.x, b = blockIdx.y;
  const int tid = threadIdx.x;
  const int base = b * NATOMS;
  const int node = base + i;
  const int g = tid >> 7;                 // chunk group 0..2
  const int t = tid & 127;
  const int lane = t & 63;
  const int isCor = t >> 6;
  const int n = lane & 15, quad = lane >> 4;

  // ---- stage: geo for all 192 j's (tid<192) + bf16 weights (tid>=192) ----
  if (tid < NATOMS){
    const int j = tid;
    const float* xi_p = xin + node*3;
    const float* xj_p = xin + (base + j)*3;
    const float dfx = xi_p[0] - xj_p[0], dfy = xi_p[1] - xj_p[1], dfz = xi_p[2] - xj_p[2];
    const float d2 = dfx*dfx + dfy*dfy + dfz*dfz;
    const float dist = sqrtf(fmaxf(d2, 1e-12f));
    const float* x0i = xyz + node*4;
    const float* x0j = xyz + (base + j)*4;
    const float q0 = x0i[0]-x0j[0], q1 = x0i[1]-x0j[1], q2 = x0i[2]-x0j[2];
    const float d0 = sqrtf(fmaxf(q0*q0 + q1*q1 + q2*q2, 1e-12f));
    s_geo[j][0] = dfx; s_geo[j][1] = dfy; s_geo[j][2] = dfz;
    s_geo[j][3] = d2;  s_geo[j][4] = d0;  s_geo[j][5] = dist;
  } else {
    const int u = tid - NATOMS;           // 0..191
    const short8* es = (const short8*)e2wb;   // 128 short8 chunks
    const short8* cs = (const short8*)c2wb;
    if (u < 128){
      const int f = u >> 2, kq = u & 3;
      *(short8*)&s_we[f][kq*8] = es[u];
    }
    if (u >= 64){
      const int c = u - 64;               // 0..127
      const int f = c >> 2, kq = c & 3;
      *(short8*)&s_wc[f][kq*8] = cs[c];
    }
  }
  __syncthreads();

  // ---- phase 1: group g computes m1/c1 for its 64 j's -> bf16 LDS ----
  {
    const int kk = t & 31, jg = t >> 5;   // jg 0..3
    const float vpe = vep[node*32 + kk];
    const float vpc = vcp[node*32 + kk];
    const float we64 = e1w[kk*66 + 64], we65 = e1w[kk*66 + 65];
    const float wc64 = c1w[kk*66 + 64], wc65 = c1w[kk*66 + 65];
#pragma unroll
    for (int jj = jg; jj < 64; jj += 4){
      const int row = g*64 + jj;
      const float d2 = s_geo[row][3], d0 = s_geo[row][4];
      const float uev = ue[(size_t)(base + row)*32 + kk];
      const float m1 = silu_f(fmaf(d2, we64, fmaf(d0, we65, vpe + uev)));
      s_m1[row][kk] = f2bf(m1);
      const float ucv = uc[(size_t)(base + row)*32 + kk];
      const float c1 = silu_f(fmaf(d2, wc64, fmaf(d0, wc65, vpc + ucv)));
      s_c1[row][kk] = f2bf(c1);
    }
  }
  __syncthreads();

  // ---- phase 2: group g, edge wave / cor wave ----
  if (isCor == 0){
    const float eb0 = e2b[n], eb1 = e2b[16 + n];
    const float ew0 = eiw[n], ew1 = eiw[16 + n];
    const float ebias = eib[0];
    float ma0 = 0.f, ma1 = 0.f;
    short8 b0 = *(const short8*)&s_we[n][quad*8];
    short8 b1 = *(const short8*)&s_we[16 + n][quad*8];
#pragma unroll
    for (int jt = 0; jt < 4; ++jt){
      short8 a = *(const short8*)&s_m1[g*64 + jt*16 + n][quad*8];
      f32x4 z = {0.f, 0.f, 0.f, 0.f};
      f32x4 acc0 = __builtin_amdgcn_mfma_f32_16x16x32_bf16(a, b0, z, 0, 0, 0);
      f32x4 acc1 = __builtin_amdgcn_mfma_f32_16x16x32_bf16(a, b1, z, 0, 0, 0);
      float m20[4], m21[4], gg[4];
#pragma unroll
      for (int r = 0; r < 4; ++r){
        m20[r] = silu_f(acc0[r] + eb0);
        m21[r] = silu_f(acc1[r] + eb1);
        gg[r] = m20[r]*ew0 + m21[r]*ew1;
      }
#pragma unroll
      for (int r = 0; r < 4; ++r){
        gg[r] += __shfl_xor(gg[r], 1);
        gg[r] += __shfl_xor(gg[r], 2);
        gg[r] += __shfl_xor(gg[r], 4);
        gg[r] += __shfl_xor(gg[r], 8);
      }
#pragma unroll
      for (int r = 0; r < 4; ++r){
        const int jglob = g*64 + jt*16 + quad*4 + r;
        const float e = (jglob == i) ? 0.0f : sigmoid_f(gg[r] + ebias);
        ma0 = fmaf(e, m20[r], ma0);
        ma1 = fmaf(e, m21[r], ma1);
      }
    }
    ma0 += __shfl_xor(ma0, 16); ma0 += __shfl_xor(ma0, 32);
    ma1 += __shfl_xor(ma1, 16); ma1 += __shfl_xor(ma1, 32);
    if (lane < 16){
      s_pm[g][lane] = ma0;
      s_pm[g][16 + lane] = ma1;
    }
  } else {
    const float cb0 = c2b[n], cb1 = c2b[16 + n];
    const float cw0 = c3w[n], cw1 = c3w[16 + n];
    const float cbias = c3b[0];
    float px = 0.f, py = 0.f, pz = 0.f;
    short8 b0 = *(const short8*)&s_wc[n][quad*8];
    short8 b1 = *(const short8*)&s_wc[16 + n][quad*8];
#pragma unroll
    for (int jt = 0; jt < 4; ++jt){
      short8 a = *(const short8*)&s_c1[g*64 + jt*16 + n][quad*8];
      f32x4 z = {0.f, 0.f, 0.f, 0.f};
      f32x4 acc0 = __builtin_amdgcn_mfma_f32_16x16x32_bf16(a, b0, z, 0, 0, 0);
      f32x4 acc1 = __builtin_amdgcn_mfma_f32_16x16x32_bf16(a, b1, z, 0, 0, 0);
      float gg[4];
#pragma unroll
      for (int r = 0; r < 4; ++r){
        gg[r] = silu_f(acc0[r] + cb0)*cw0 + silu_f(acc1[r] + cb1)*cw1;
      }
#pragma unroll
      for (int r = 0; r < 4; ++r){
        gg[r] += __shfl_xor(gg[r], 1);
        gg[r] += __shfl_xor(gg[r], 2);
        gg[r] += __shfl_xor(gg[r], 4);
        gg[r] += __shfl_xor(gg[r], 8);
      }
#pragma unroll
      for (int r = 0; r < 4; ++r){
        const int row = g*64 + jt*16 + quad*4 + r;
        const float s = (gg[r] + cbias) * fast_rcp(s_geo[row][5] + 1.0f);
        px = fmaf(s, s_geo[row][0], px);
        py = fmaf(s, s_geo[row][1], py);
        pz = fmaf(s, s_geo[row][2], pz);
      }
    }
    px += __shfl_xor(px, 16); px += __shfl_xor(px, 32);
    py += __shfl_xor(py, 16); py += __shfl_xor(py, 32);
    pz += __shfl_xor(pz, 16); pz += __shfl_xor(pz, 32);
    if (lane == 0){ s_pxc[g][0] = px; s_pxc[g][1] = py; s_pxc[g][2] = pz; }
  }
  __syncthreads();
  if (tid >= 64) return;                 // post on wave0 only

  const int f = tid & 31;                // lanes 32-63 mirror 0-31 (benign)
  const float mgf = s_pm[0][f] + s_pm[1][f] + s_pm[2][f];
  const float hlf = hln[node*32 + f];

  // node MLP via shfl broadcasts
  float a = n1b[f];
  const float* w1 = n1w + f*64;
#pragma unroll
  for (int k = 0; k < 32; ++k) a = fmaf(__shfl(hlf, k, 64), w1[k], a);
#pragma unroll
  for (int k = 0; k < 32; ++k) a = fmaf(__shfl(mgf, k, 64), w1[32 + k], a);
  const float n1v = silu_f(a);
  float o = n2b[f];
  const float* w2 = n2w + f*32;
#pragma unroll
  for (int k = 0; k < 32; ++k) o = fmaf(__shfl(n1v, k, 64), w2[k], o);
  const float ho = hlf + o;

  // x update: xn = LN(x_i) + xc
  float xn0, xn1, xn2;
  {
    const float* xr = xin + node*3;
    const float x0 = xr[0], x1 = xr[1], x2 = xr[2];
    const float mx = (x0 + x1 + x2) * (1.0f/3.0f);
    const float v0 = x0-mx, v1 = x1-mx, v2 = x2-mx;
    const float r = rsqrtf((v0*v0 + v1*v1 + v2*v2)*(1.0f/3.0f) + 1e-5f);
    xn0 = fmaf(v0*r, lnxg[0], lnxb[0]) + s_pxc[0][0] + s_pxc[1][0] + s_pxc[2][0];
    xn1 = fmaf(v1*r, lnxg[1], lnxb[1]) + s_pxc[0][1] + s_pxc[1][1] + s_pxc[2][1];
    xn2 = fmaf(v2*r, lnxg[2], lnxb[2]) + s_pxc[0][2] + s_pxc[1][2] + s_pxc[2][2];
  }

  if (!lastl){
    if (tid == 0){
      float* xo = xout + node*3;
      xo[0] = xn0; xo[1] = xn1; xo[2] = xn2;
    }
    // LN(ho) across 32 lanes (butterfly; lanes 32-63 mirror)
    float s = ho;
    s += __shfl_xor(s, 1); s += __shfl_xor(s, 2); s += __shfl_xor(s, 4);
    s += __shfl_xor(s, 8); s += __shfl_xor(s, 16);
    const float m = s * (1.0f/32.0f);
    const float d = ho - m;
    float vv = d*d;
    vv += __shfl_xor(vv, 1); vv += __shfl_xor(vv, 2); vv += __shfl_xor(vv, 4);
    vv += __shfl_xor(vv, 8); vv += __shfl_xor(vv, 16);
    const float r = rsqrtf(vv*(1.0f/32.0f) + 1e-5f);
    const float hl = fmaf(d*r, lnhg_n[f], lnhb_n[f]);
    if (tid < 32) hln_n[node*32 + f] = hl;

    const float* we = e1w_n + f*66;
    const float* wc = c1w_n + f*66;
    float sv = e1b_n[f], su = 0.f, cv = c1b_n[f], cu = 0.f;
#pragma unroll
    for (int k = 0; k < 32; ++k){
      const float tkk = __shfl(hl, k, 64);
      sv = fmaf(tkk, we[k], sv);
      su = fmaf(tkk, we[32 + k], su);
      cv = fmaf(tkk, wc[k], cv);
      cu = fmaf(tkk, wc[32 + k], cu);
    }
    if (tid < 32){
      vep_n[node*32 + f] = sv;
      ue_n [node*32 + f] = su;
      vcp_n[node*32 + f] = cv;
      uc_n [node*32 + f] = cu;
    }
  } else {
    // output heads directly
    float hh = how[f] * ho;
    hh += __shfl_xor(hh, 1); hh += __shfl_xor(hh, 2); hh += __shfl_xor(hh, 4);
    hh += __shfl_xor(hh, 8); hh += __shfl_xor(hh, 16);
    if (tid == 0) dout[node*4 + 3] = hh + hob[0];
    if (tid < 3){
      const int c = tid;
      float oo = xob[c];
      oo = fmaf(xn0, xow[c*3 + 0], oo);
      oo = fmaf(xn1, xow[c*3 + 1], oo);
      oo = fmaf(xn2, xow[c*3 + 2], oo);
      dout[node*4 + c] = oo - xyz[node*4 + c];
    }
  }
}

extern "C" void kernel_launch(void* const* d_in, const int* in_sizes, int n_in,
                              void* d_out, int out_size, void* d_ws, size_t ws_size,
                              hipStream_t stream)
{
  const float* xyz      = (const float*)d_in[0];
  const float* pdf      = (const float*)d_in[1];
  const float* t        = (const float*)d_in[2];
  const float* emb_in_w = (const float*)d_in[3];
  const float* emb_in_b = (const float*)d_in[4];
  const float* emb_out_w= (const float*)d_in[5];
  const float* emb_out_b= (const float*)d_in[6];
  const float* x_out_w  = (const float*)d_in[7];
  const float* x_out_b  = (const float*)d_in[8];
  const float* pdf_w    = (const float*)d_in[9];
  const float* pdf_b    = (const float*)d_in[10];
  const float* g1w      = (const float*)d_in[11];
  const float* g1b      = (const float*)d_in[12];
  const float* g2w      = (const float*)d_in[13];
  const float* g2b      = (const float*)d_in[14];
  const float* g3w      = (const float*)d_in[15];
  const float* g3b      = (const float*)d_in[16];
  const float* gamma0   = (const float*)d_in[17];
  const float* gamma1   = (const float*)d_in[18];
  const float* lnhg     = (const float*)d_in[19];
  const float* lnhb     = (const float*)d_in[20];
  const float* lnxg     = (const float*)d_in[21];
  const float* lnxb     = (const float*)d_in[22];
  const float* e1w      = (const float*)d_in[23];
  const float* e1b      = (const float*)d_in[24];
  const float* e2w      = (const float*)d_in[25];
  const float* e2b      = (const float*)d_in[26];
  const float* eiw      = (const float*)d_in[27];
  const float* eib      = (const float*)d_in[28];
  const float* n1w      = (const float*)d_in[29];
  const float* n1b      = (const float*)d_in[30];
  const float* n2w      = (const float*)d_in[31];
  const float* n2b      = (const float*)d_in[32];
  const float* c1w      = (const float*)d_in[33];
  const float* c1b      = (const float*)d_in[34];
  const float* c2w      = (const float*)d_in[35];
  const float* c2b      = (const float*)d_in[36];
  const float* c3w      = (const float*)d_in[37];
  const float* c3b      = (const float*)d_in[38];

  const int NTOT = BATCH*NATOMS;          // 1536 nodes
  float* ws   = (float*)d_ws;
  float* temb = ws;                        // 8
  float* pdfe = ws + 8;                    // 80 (pad to 96)
  unsigned short* e2wb = (unsigned short*)(ws + 96);   // 4096 ushort
  unsigned short* c2wb = e2wb + 4096;                  // 4096 ushort
  float* p0   = ws + 96 + 4096;            // (8192 ushort = 4096 floats)
  float* xbA  = p0;                float* xbB  = xbA + NTOT*3;
  float* hlnA = xbB  + NTOT*3;     float* hlnB = hlnA + NTOT*32;
  float* ueA  = hlnB + NTOT*32;    float* ueB  = ueA  + NTOT*32;
  float* ucA  = ueB  + NTOT*32;    float* ucB  = ucA  + NTOT*32;
  float* vepA = ucB  + NTOT*32;    float* vepB = vepA + NTOT*32;
  float* vcpA = vepB + NTOT*32;    float* vcpB = vcpA + NTOT*32;

  float* xb[2]  = {xbA,  xbB};
  float* hlnP[2]= {hlnA, hlnB};
  float* ueP[2] = {ueA,  ueB};
  float* ucP[2] = {ucA,  ucB};
  float* vepP[2]= {vepA, vepB};
  float* vcpP[2]= {vcpA, vcpB};

  k_prelude<<<104, 256, 0, stream>>>(pdf, t, pdf_w, pdf_b,
      g1w, g1b, g2w, g2b, g3w, g3b, gamma0, gamma1,
      e2w, c2w, e2wb, c2wb, temb, pdfe);
  k_embed_node<<<NTOT/8, 256, 0, stream>>>(
      xyz, temb, pdfe, emb_in_w, emb_in_b,
      lnhg, lnhb, e1w, e1b, c1w, c1b,
      xbA, hlnA, ueA, ucA, vepA, vcpA);

  for (int l = 0; l < 4; ++l){
    const int p = l & 1;
    const int nl = (l < 3) ? (l + 1) : 3;  // next-layer weights (unused l==3)
    k_pair<<<dim3(NATOMS, BATCH), 384, 0, stream>>>(
        xb[p], xyz, hlnP[p], ueP[p], ucP[p], vepP[p], vcpP[p],
        e1w + l*2112, c1w + l*2112,
        e2wb + l*1024, c2wb + l*1024,
        e2b + l*32, eiw + l*32, eib + l,
        c2b + l*32, c3w + l*32, c3b + l,
        n1w + l*2048, n1b + l*32, n2w + l*1024, n2b + l*32,
        lnxg + l*3, lnxb + l*3,
        lnhg + nl*32, lnhb + nl*32,
        e1w + nl*2112, e1b + nl*32, c1w + nl*2112, c1b + nl*32,
        hlnP[1-p], ueP[1-p], ucP[1-p], vepP[1-p], vcpP[1-p], xb[1-p],
        emb_out_w, emb_out_b, x_out_w, x_out_b,
        (float*)d_out, (l == 3) ? 1 : 0);
  }
}